// Round 18
// baseline (529.151 us; speedup 1.0000x reference)
//
#include <hip/hip_runtime.h>
#include <hip/hip_bf16.h>

#define LOG2E 1.4426950408889634f
#define LOG2LOG2E 0.5287663729448977f

typedef unsigned int u32;
typedef float f32x16 __attribute__((ext_vector_type(16)));
typedef short sh8 __attribute__((ext_vector_type(8)));

union FR { u32 u[4]; sh8 s; };

__device__ __forceinline__ u32 cvt_pk_bf16(float lo, float hi){
  u32 r;
  asm volatile("v_cvt_pk_bf16_f32 %0, %1, %2" : "=v"(r) : "v"(lo), "v"(hi));
  return r;
}

__device__ __forceinline__ float asum16(const float* s){
  float a0=s[0]+s[8],  a1=s[1]+s[9],  a2=s[2]+s[10], a3=s[3]+s[11];
  float a4=s[4]+s[12], a5=s[5]+s[13], a6=s[6]+s[14], a7=s[7]+s[15];
  a0+=a4; a1+=a5; a2+=a6; a3+=a7;
  a0+=a2; a1+=a3;
  return a0+a1;
}

template<int W>
__device__ __forceinline__ float wred_max(float v){
  #pragma unroll
  for (int o=1;o<W;o<<=1) v = fmaxf(v, __shfl_xor(v,o));
  return v;
}
template<int W>
__device__ __forceinline__ float wred_sum(float v){
  #pragma unroll
  for (int o=1;o<W;o<<=1) v += __shfl_xor(v,o);
  return v;
}

// ---------------- adj -> bitmask (transposed: mkT[word][row]) ----------------
template<int NW>
__global__ __launch_bounds__(256) void k_mask(const int* __restrict__ adj, u32* __restrict__ mkT, int N){
  int id = blockIdx.x*256 + threadIdx.x;
  int row = id / NW, word = id - row*NW;
  const int4* src = (const int4*)(adj + (size_t)row*N + word*32);
  u32 m = 0;
  #pragma unroll
  for (int g=0; g<8; g++){
    int4 v = src[g];
    if (v.x>0) m |= 1u<<(g*4+0);
    if (v.y>0) m |= 1u<<(g*4+1);
    if (v.z>0) m |= 1u<<(g*4+2);
    if (v.w>0) m |= 1u<<(g*4+3);
  }
  mkT[(size_t)word*N + row] = m;
}

// ---------------- pre_a: Wh = (x @ W) @ linW + linb ----------------
template<int FIN, int F>
__global__ __launch_bounds__(256) void k_pre_a(const float* __restrict__ xg, const float* __restrict__ Wg,
    const float* __restrict__ lWg, const float* __restrict__ lbg, float* __restrict__ Whg, int N)
{
  const int h = blockIdx.y;
  const int row = blockIdx.x*256 + threadIdx.x;
  __shared__ float Wl[FIN*F];
  __shared__ float lWl[F*F];
  __shared__ float lbl[F];
  for (int i=threadIdx.x;i<FIN*F;i+=256) Wl[i]=Wg[(size_t)h*FIN*F+i];
  for (int i=threadIdx.x;i<F*F;i+=256) lWl[i]=lWg[(size_t)h*F*F+i];
  if (threadIdx.x<F) lbl[threadIdx.x]=lbg[h*F+threadIdx.x];
  __syncthreads();
  float t[F];
  #pragma unroll
  for (int c=0;c<F;c++) t[c]=0.f;
  const float4* xr = (const float4*)(xg + (size_t)row*FIN);
  for (int k4=0;k4<FIN/4;k4++){
    float4 xv = xr[k4];
    float xs[4]={xv.x,xv.y,xv.z,xv.w};
    #pragma unroll
    for (int kk=0;kk<4;kk++){
      float x1 = xs[kk];
      const float* wrow = Wl + (k4*4+kk)*F;
      #pragma unroll
      for (int c=0;c<F;c++) t[c] = fmaf(x1, wrow[c], t[c]);
    }
  }
  float wh[F];
  #pragma unroll
  for (int c=0;c<F;c++) wh[c]=lbl[c];
  #pragma unroll
  for (int k=0;k<F;k++){
    float tv=t[k];
    #pragma unroll
    for (int c=0;c<F;c++) wh[c]=fmaf(tv, lWl[k*F+c], wh[c]);
  }
  float4* dst=(float4*)(Whg + ((size_t)h*N+row)*F);
  #pragma unroll
  for (int c4=0;c4<F/4;c4++) dst[c4]=make_float4(wh[c4*4],wh[c4*4+1],wh[c4*4+2],wh[c4*4+3]);
}

// ---------------- pre_b: one thread per row (spill-proof, pre_a-style) ----------------
// qkv = Wh @ qkvW + qkvb ; f1/f2 = Wh @ a. Columns in 8-wide all-static chunks.
template<int F>
__global__ __launch_bounds__(256) void k_pre_b(const float* __restrict__ Whg, const float* __restrict__ qWg,
   const float* __restrict__ qbg, const float* __restrict__ ag,
   float* __restrict__ qg, float* __restrict__ kg, float* __restrict__ vg,
   float* __restrict__ f1g, float* __restrict__ f2g, int N)
{
  const int h = blockIdx.y;
  const int row = blockIdx.x*256 + threadIdx.x;
  __shared__ float qWl[F*3*F];
  __shared__ float qbl[3*F];
  __shared__ float al[2*F];
  for (int i=threadIdx.x;i<F*3*F;i+=256) qWl[i]=qWg[(size_t)h*F*3*F+i];
  if (threadIdx.x<3*F) qbl[threadIdx.x]=qbg[h*3*F+threadIdx.x];
  if (threadIdx.x<2*F) al[threadIdx.x]=ag[h*2*F+threadIdx.x];
  __syncthreads();
  float wh[F];
  {
    const float4* wsrc = (const float4*)(Whg + ((size_t)h*N+row)*F);
    #pragma unroll
    for (int c4=0;c4<F/4;c4++){
      float4 t = wsrc[c4];
      wh[c4*4]=t.x; wh[c4*4+1]=t.y; wh[c4*4+2]=t.z; wh[c4*4+3]=t.w;
    }
  }
  // f1/f2
  {
    float s1=0.f, s2=0.f;
    #pragma unroll
    for (int k=0;k<F;k++){
      s1 = fmaf(wh[k], al[k],   s1);
      s2 = fmaf(wh[k], al[F+k], s2);
    }
    f1g[(size_t)h*N+row]=s1;
    f2g[(size_t)h*N+row]=s2;
  }
  // qkv in 8-col chunks (each chunk entirely within one of q/k/v: regions 8-aligned)
  size_t base = ((size_t)h*N+row)*F;
  for (int c0=0;c0<3*F;c0+=8){
    float acc[8];
    #pragma unroll
    for (int j=0;j<8;j++) acc[j]=qbl[c0+j];
    for (int k=0;k<F;k++){
      float wv = wh[k];
      const float* qw = qWl + k*3*F + c0;
      #pragma unroll
      for (int j=0;j<8;j++) acc[j]=fmaf(wv, qw[j], acc[j]);
    }
    float* dst;
    int reg = c0 / F, off = c0 - reg*F;
    if      (reg==0) dst = qg + base + off;
    else if (reg==1) dst = kg + base + off;
    else             dst = vg + base + off;
    *(float4*)dst     = make_float4(acc[0],acc[1],acc[2],acc[3]);
    *(float4*)(dst+4) = make_float4(acc[4],acc[5],acc[6],acc[7]);
  }
}

// ---------------- sweep1 MFMA (layer1, F=32, d=8), fixed-max (m=0) ----------------
template<int S>
__global__ __launch_bounds__(256,4) void k_sweep1_mfma32(const float* __restrict__ qg, const float* __restrict__ kg,
    const float* __restrict__ vg, float* __restrict__ pml, float* __restrict__ pw, int N, float qscale)
{
  constexpr int F=32, LROW=33;
  const int h = blockIdx.z;
  const int sc = blockIdx.y;
  const int JC = N/S;
  const int wid = threadIdx.x>>6;
  const int lane = threadIdx.x&63;
  const int l31 = lane&31;
  const int half = lane>>5;
  const int itile = blockIdx.x*4 + wid;
  const int i = itile*32 + l31;
  __shared__ float vt[32*LROW];

  sh8 qf[4];
  {
    const float* qrow = qg + ((size_t)h*N + i)*F;
    #pragma unroll
    for (int hh=0;hh<4;hh++){
      FR u;
      #pragma unroll
      for (int p=0;p<4;p++){
        float lo = half? 0.f : qrow[hh*8+2*p]*qscale;
        float hi = half? 0.f : qrow[hh*8+2*p+1]*qscale;
        u.u[p] = cvt_pk_bf16(lo,hi);
      }
      qf[hh]=u.s;
    }
  }
  f32x16 C, Zv;
  #pragma unroll
  for (int r=0;r<16;r++){ C[r]=0.f; Zv[r]=0.f; }
  float l[4];
  #pragma unroll
  for (int hh=0;hh<4;hh++) l[hh]=0.f;
  const sh8 zf = {0,0,0,0,0,0,0,0};

  const int j0 = sc*JC;
  for (int jt=0; jt<JC; jt+=32){
    __syncthreads();
    {
      const float4* vs = (const float4*)(vg + ((size_t)h*N + j0+jt)*F);
      int idx = threadIdx.x;
      int j = idx>>3, c4 = idx&7;
      float4 b = vs[idx];
      float* vd = vt + j*LROW + c4*4;
      vd[0]=b.x; vd[1]=b.y; vd[2]=b.z; vd[3]=b.w;
    }
    __syncthreads();
    const float* krow = kg + ((size_t)h*N + j0+jt + l31)*F;
    sh8 vA[2];
    #pragma unroll
    for (int c=0;c<2;c++){
      FR u;
      #pragma unroll
      for (int p=0;p<4;p++){
        int jl = c*16 + half*8 + 2*p;
        u.u[p]=cvt_pk_bf16(vt[jl*LROW + l31], vt[(jl+1)*LROW + l31]);
      }
      vA[c]=u.s;
    }
    #pragma unroll
    for (int hh=0;hh<4;hh++){
      sh8 kf;
      {
        FR u;
        float4 ka = *(const float4*)(krow + hh*8);
        float4 kb = *(const float4*)(krow + hh*8 + 4);
        u.u[0]=cvt_pk_bf16(ka.x,ka.y);
        u.u[1]=cvt_pk_bf16(ka.z,ka.w);
        u.u[2]=cvt_pk_bf16(kb.x,kb.y);
        u.u[3]=cvt_pk_bf16(kb.z,kb.w);
        kf=u.s;   // upper K-half garbage harmless: qf upper half is 0
      }
      f32x16 Sacc = __builtin_amdgcn_mfma_f32_32x32x16_bf16(kf, qf[hh], Zv, 0,0,0);
      float p[16];
      #pragma unroll
      for (int r=0;r<16;r++) p[r] = exp2f(Sacc[r]);
      l[hh] += asum16(p);
      const bool own = ((l31>>3)==hh);
      #pragma unroll
      for (int c=0;c<2;c++){
        u32 a01 = cvt_pk_bf16(p[c*8+0], p[c*8+1]);
        u32 a23 = cvt_pk_bf16(p[c*8+2], p[c*8+3]);
        u32 b01 = cvt_pk_bf16(p[c*8+4], p[c*8+5]);
        u32 b23 = cvt_pk_bf16(p[c*8+6], p[c*8+7]);
        u32 a01s = __shfl_xor(a01,32);
        u32 a23s = __shfl_xor(a23,32);
        u32 b01s = __shfl_xor(b01,32);
        u32 b23s = __shfl_xor(b23,32);
        FR bf;
        bf.u[0] = half? b01s : a01;
        bf.u[1] = half? b23s : a23;
        bf.u[2] = half? b01  : a01s;
        bf.u[3] = half? b23  : a23s;
        sh8 av = own ? vA[c] : zf;
        C = __builtin_amdgcn_mfma_f32_32x32x16_bf16(av, bf.s, C, 0,0,0);
      }
    }
  }
  float lt[4];
  #pragma unroll
  for (int hh=0;hh<4;hh++) lt[hh] = l[hh] + __shfl_xor(l[hh],32);
  if (half==0){
    float* pb = pml + ((size_t)(h*S+sc)*8)*N + i;
    #pragma unroll
    for (int hh=0;hh<4;hh++){ pb[(size_t)hh*N]=0.f; pb[(size_t)(4+hh)*N]=lt[hh]; }
  }
  {
    float* pv = pw + ((size_t)(h*S+sc)*N + i)*F;
    #pragma unroll
    for (int hh=0;hh<4;hh++){
      *(float4*)(pv + 8*hh + 4*half) = make_float4(C[hh*4],C[hh*4+1],C[hh*4+2],C[hh*4+3]);
    }
  }
}

// ---------------- sweep2 MFMA (layer1, F=32, d=8), fixed-max, transposed mask ----------------
template<int S>
__global__ __launch_bounds__(256,4) void k_sweep2_mfma32(const float* __restrict__ qg, const float* __restrict__ kg,
    const float* __restrict__ whg, const float* __restrict__ f1g, const float* __restrict__ f2g,
    const float* __restrict__ mstar, const float* __restrict__ invl, const u32* __restrict__ mkT,
    float* __restrict__ p2ml, float* __restrict__ php, int N, float qscale)
{
  constexpr int F=32, LROW=33;
  const int h = blockIdx.z;
  const int sc = blockIdx.y;
  const int JC = N/S;
  const int wid = threadIdx.x>>6;
  const int lane = threadIdx.x&63;
  const int l31 = lane&31;
  const int half = lane>>5;
  const int itile = blockIdx.x*4 + wid;
  const int i = itile*32 + l31;
  __shared__ float wt[32*LROW];
  __shared__ float f2s[32];

  sh8 qf[4];
  {
    const float* qrow = qg + ((size_t)h*N + i)*F;
    #pragma unroll
    for (int hh=0;hh<4;hh++){
      FR u;
      #pragma unroll
      for (int p=0;p<4;p++){
        float lo = half? 0.f : qrow[hh*8+2*p]*qscale;
        float hi = half? 0.f : qrow[hh*8+2*p+1]*qscale;
        u.u[p] = cvt_pk_bf16(lo,hi);
      }
      qf[hh]=u.s;
    }
  }
  float cc[4];
  #pragma unroll
  for (int hh=0;hh<4;hh++){
    float msv = mstar[((size_t)(h*4+hh))*N+i];
    float ilv = invl [((size_t)(h*4+hh))*N+i];
    cc[hh] = log2f(ilv) - msv + LOG2LOG2E;
  }
  const float f1 = f1g[(size_t)h*N+i];
  f32x16 C, Zv;
  #pragma unroll
  for (int r=0;r<16;r++){ C[r]=0.f; Zv[r]=0.f; }
  float L=0.f;

  const int j0 = sc*JC;
  for (int jt=0; jt<JC; jt+=32){
    __syncthreads();
    {
      const float4* ws = (const float4*)(whg + ((size_t)h*N + j0+jt)*F);
      int idx = threadIdx.x;
      int j = idx>>3, c4 = idx&7;
      float4 b = ws[idx];
      float* wd = wt + j*LROW + c4*4;
      wd[0]=b.x; wd[1]=b.y; wd[2]=b.z; wd[3]=b.w;
      if (threadIdx.x<32) f2s[threadIdx.x] = f2g[(size_t)h*N + j0+jt+threadIdx.x];
    }
    __syncthreads();
    u32 mw = mkT[(size_t)((j0+jt)>>5)*N + i];     // coalesced transposed mask
    const float* krow = kg + ((size_t)h*N + j0+jt + l31)*F;
    float ds[16];
    #pragma unroll
    for (int r=0;r<16;r++) ds[r]=0.f;
    #pragma unroll
    for (int hh=0;hh<4;hh++){
      sh8 kf;
      {
        FR u;
        float4 ka = *(const float4*)(krow + hh*8);
        float4 kb = *(const float4*)(krow + hh*8 + 4);
        u.u[0]=cvt_pk_bf16(ka.x,ka.y);
        u.u[1]=cvt_pk_bf16(ka.z,ka.w);
        u.u[2]=cvt_pk_bf16(kb.x,kb.y);
        u.u[3]=cvt_pk_bf16(kb.z,kb.w);
        kf=u.s;
      }
      f32x16 Sacc = __builtin_amdgcn_mfma_f32_32x32x16_bf16(kf, qf[hh], Zv, 0,0,0);
      float ch = cc[hh];
      #pragma unroll
      for (int r=0;r<16;r++) ds[r] += exp2f(Sacc[r] + ch);
    }
    #pragma unroll
    for (int r=0;r<16;r++){
      int jo = (r&3)+8*(r>>2)+4*half;
      float e = f1 + f2s[jo];
      e = (e>=0.f)? e : 0.2f*e;
      float ev = exp2f(fmaf(e, LOG2E, ds[r]));
      ds[r] = ((mw>>jo)&1u) ? ev : 0.f;
    }
    L += asum16(ds);
    #pragma unroll
    for (int c=0;c<2;c++){
      sh8 whA;
      {
        FR u;
        #pragma unroll
        for (int p=0;p<4;p++){
          int jl = c*16 + half*8 + 2*p;
          u.u[p]=cvt_pk_bf16(wt[jl*LROW + l31], wt[(jl+1)*LROW + l31]);
        }
        whA=u.s;
      }
      u32 a01 = cvt_pk_bf16(ds[c*8+0], ds[c*8+1]);
      u32 a23 = cvt_pk_bf16(ds[c*8+2], ds[c*8+3]);
      u32 b01 = cvt_pk_bf16(ds[c*8+4], ds[c*8+5]);
      u32 b23 = cvt_pk_bf16(ds[c*8+6], ds[c*8+7]);
      u32 a01s = __shfl_xor(a01,32);
      u32 a23s = __shfl_xor(a23,32);
      u32 b01s = __shfl_xor(b01,32);
      u32 b23s = __shfl_xor(b23,32);
      FR bf;
      bf.u[0] = half? b01s : a01;
      bf.u[1] = half? b23s : a23;
      bf.u[2] = half? b01  : a01s;
      bf.u[3] = half? b23  : a23s;
      C = __builtin_amdgcn_mfma_f32_32x32x16_bf16(whA, bf.s, C, 0,0,0);
    }
  }
  L = L + __shfl_xor(L,32);
  if (half==0){
    float* pb = p2ml + ((size_t)(h*S+sc)*2)*N + i;
    pb[0]=0.f; pb[(size_t)N]=L;
  }
  {
    float* pv = php + ((size_t)(h*S+sc)*N + i)*F;
    #pragma unroll
    for (int g=0;g<4;g++)
      *(float4*)(pv + 8*g + 4*half) = make_float4(C[g*4],C[g*4+1],C[g*4+2],C[g*4+3]);
  }
}

// ---------------- sweep1 MFMA (layer2, F=64, d=16), fixed-max ----------------
template<int S>
__global__ __launch_bounds__(256,4) void k_sweep1_mfma64(const float* __restrict__ qg, const float* __restrict__ kg,
    const float* __restrict__ vg, float* __restrict__ pml, float* __restrict__ pw, int N, float qscale)
{
  constexpr int F=64, LROW=65;
  const int h = blockIdx.z;
  const int sc = blockIdx.y;
  const int JC = N/S;
  const int wid = threadIdx.x>>6;
  const int lane = threadIdx.x&63;
  const int l31 = lane&31;
  const int half = lane>>5;
  const int itile = blockIdx.x*4 + wid;
  const int i = itile*32 + l31;
  __shared__ float vt[32*LROW];

  sh8 qf[4];
  {
    const float* qrow = qg + ((size_t)h*N + i)*F;
    #pragma unroll
    for (int hh=0;hh<4;hh++){
      FR u;
      #pragma unroll
      for (int p=0;p<4;p++)
        u.u[p] = cvt_pk_bf16(qrow[hh*16 + 8*half + 2*p]*qscale, qrow[hh*16 + 8*half + 2*p+1]*qscale);
      qf[hh]=u.s;
    }
  }
  f32x16 C0, C1, Zv;
  #pragma unroll
  for (int r=0;r<16;r++){ C0[r]=0.f; C1[r]=0.f; Zv[r]=0.f; }
  float l[4];
  #pragma unroll
  for (int hh=0;hh<4;hh++) l[hh]=0.f;
  const sh8 zf = {0,0,0,0,0,0,0,0};

  const int j0 = sc*JC;
  for (int jt=0; jt<JC; jt+=32){
    __syncthreads();
    {
      const float4* vs = (const float4*)(vg + ((size_t)h*N + j0+jt)*F);
      #pragma unroll
      for (int q2=0;q2<2;q2++){
        int idx = q2*256 + threadIdx.x;
        int j = idx>>4, c4 = idx&15;
        float4 b = vs[idx];
        float* vd = vt + j*LROW + c4*4;
        vd[0]=b.x; vd[1]=b.y; vd[2]=b.z; vd[3]=b.w;
      }
    }
    __syncthreads();
    const float* krow = kg + ((size_t)h*N + j0+jt + l31)*F;
    sh8 vA[2][2];
    #pragma unroll
    for (int ch=0;ch<2;ch++)
      #pragma unroll
      for (int c=0;c<2;c++){
        FR u;
        #pragma unroll
        for (int p=0;p<4;p++){
          int jl = c*16 + half*8 + 2*p;
          u.u[p]=cvt_pk_bf16(vt[jl*LROW + ch*32 + l31], vt[(jl+1)*LROW + ch*32 + l31]);
        }
        vA[ch][c]=u.s;
      }
    #pragma unroll
    for (int hh=0;hh<4;hh++){
      sh8 kf;
      {
        FR u;
        float4 ka = *(const float4*)(krow + hh*16 + 8*half);
        float4 kb = *(const float4*)(krow + hh*16 + 8*half + 4);
        u.u[0]=cvt_pk_bf16(ka.x,ka.y);
        u.u[1]=cvt_pk_bf16(ka.z,ka.w);
        u.u[2]=cvt_pk_bf16(kb.x,kb.y);
        u.u[3]=cvt_pk_bf16(kb.z,kb.w);
        kf=u.s;
      }
      f32x16 Sacc = __builtin_amdgcn_mfma_f32_32x32x16_bf16(kf, qf[hh], Zv, 0,0,0);
      f32x16 &Cr = (hh>>1)? C1 : C0;
      float p[16];
      #pragma unroll
      for (int r=0;r<16;r++) p[r] = exp2f(Sacc[r]);
      l[hh] += asum16(p);
      const bool own = ((l31>>4) == (hh&1));
      #pragma unroll
      for (int c=0;c<2;c++){
        u32 a01 = cvt_pk_bf16(p[c*8+0], p[c*8+1]);
        u32 a23 = cvt_pk_bf16(p[c*8+2], p[c*8+3]);
        u32 b01 = cvt_pk_bf16(p[c*8+4], p[c*8+5]);
        u32 b23 = cvt_pk_bf16(p[c*8+6], p[c*8+7]);
        u32 a01s = __shfl_xor(a01,32);
        u32 a23s = __shfl_xor(a23,32);
        u32 b01s = __shfl_xor(b01,32);
        u32 b23s = __shfl_xor(b23,32);
        FR bf;
        bf.u[0] = half? b01s : a01;
        bf.u[1] = half? b23s : a23;
        bf.u[2] = half? b01  : a01s;
        bf.u[3] = half? b23  : a23s;
        sh8 av = own ? vA[hh>>1][c] : zf;
        Cr = __builtin_amdgcn_mfma_f32_32x32x16_bf16(av, bf.s, Cr, 0,0,0);
      }
    }
  }
  float lt[4];
  #pragma unroll
  for (int hh=0;hh<4;hh++) lt[hh] = l[hh] + __shfl_xor(l[hh],32);
  if (half==0){
    float* pb = pml + ((size_t)(h*S+sc)*8)*N + i;
    #pragma unroll
    for (int hh=0;hh<4;hh++){ pb[(size_t)hh*N]=0.f; pb[(size_t)(4+hh)*N]=lt[hh]; }
  }
  {
    float* pv = pw + ((size_t)(h*S+sc)*N + i)*F;
    #pragma unroll
    for (int g=0;g<4;g++){
      *(float4*)(pv + 8*g + 4*half)      = make_float4(C0[g*4],C0[g*4+1],C0[g*4+2],C0[g*4+3]);
      *(float4*)(pv + 32 + 8*g + 4*half) = make_float4(C1[g*4],C1[g*4+1],C1[g*4+2],C1[g*4+3]);
    }
  }
}

// ---------------- sweep2 MFMA (layer2, F=64, d=16), fixed-max, transposed mask ----------------
template<int S>
__global__ __launch_bounds__(256,4) void k_sweep2_mfma64(const float* __restrict__ qg, const float* __restrict__ kg,
    const float* __restrict__ whg, const float* __restrict__ f1g, const float* __restrict__ f2g,
    const float* __restrict__ mstar, const float* __restrict__ invl, const u32* __restrict__ mkT,
    float* __restrict__ p2ml, float* __restrict__ php, int N, float qscale)
{
  constexpr int F=64, LROW=65;
  const int h = blockIdx.z;
  const int sc = blockIdx.y;
  const int JC = N/S;
  const int wid = threadIdx.x>>6;
  const int lane = threadIdx.x&63;
  const int l31 = lane&31;
  const int half = lane>>5;
  const int itile = blockIdx.x*4 + wid;
  const int i = itile*32 + l31;
  __shared__ float wt[32*LROW];
  __shared__ float f2s[32];

  sh8 qf[4];
  {
    const float* qrow = qg + ((size_t)h*N + i)*F;
    #pragma unroll
    for (int hh=0;hh<4;hh++){
      FR u;
      #pragma unroll
      for (int p=0;p<4;p++)
        u.u[p] = cvt_pk_bf16(qrow[hh*16 + 8*half + 2*p]*qscale, qrow[hh*16 + 8*half + 2*p+1]*qscale);
      qf[hh]=u.s;
    }
  }
  float cc[4];
  #pragma unroll
  for (int hh=0;hh<4;hh++){
    float msv = mstar[((size_t)(h*4+hh))*N+i];
    float ilv = invl [((size_t)(h*4+hh))*N+i];
    cc[hh] = log2f(ilv) - msv + LOG2LOG2E;
  }
  const float f1 = f1g[(size_t)h*N+i];
  f32x16 C0, C1, Zv;
  #pragma unroll
  for (int r=0;r<16;r++){ C0[r]=0.f; C1[r]=0.f; Zv[r]=0.f; }
  float L=0.f;

  const int j0 = sc*JC;
  for (int jt=0; jt<JC; jt+=32){
    __syncthreads();
    {
      const float4* ws = (const float4*)(whg + ((size_t)h*N + j0+jt)*F);
      #pragma unroll
      for (int q2=0;q2<2;q2++){
        int idx = q2*256 + threadIdx.x;
        int j = idx>>4, c4 = idx&15;
        float4 b = ws[idx];
        float* wd = wt + j*LROW + c4*4;
        wd[0]=b.x; wd[1]=b.y; wd[2]=b.z; wd[3]=b.w;
      }
      if (threadIdx.x<32) f2s[threadIdx.x] = f2g[(size_t)h*N + j0+jt+threadIdx.x];
    }
    __syncthreads();
    u32 mw = mkT[(size_t)((j0+jt)>>5)*N + i];
    const float* krow = kg + ((size_t)h*N + j0+jt + l31)*F;
    float ds[16];
    #pragma unroll
    for (int r=0;r<16;r++) ds[r]=0.f;
    #pragma unroll
    for (int hh=0;hh<4;hh++){
      sh8 kf;
      {
        FR u;
        float4 ka = *(const float4*)(krow + hh*16 + 8*half);
        float4 kb = *(const float4*)(krow + hh*16 + 8*half + 4);
        u.u[0]=cvt_pk_bf16(ka.x,ka.y);
        u.u[1]=cvt_pk_bf16(ka.z,ka.w);
        u.u[2]=cvt_pk_bf16(kb.x,kb.y);
        u.u[3]=cvt_pk_bf16(kb.z,kb.w);
        kf=u.s;
      }
      f32x16 Sacc = __builtin_amdgcn_mfma_f32_32x32x16_bf16(kf, qf[hh], Zv, 0,0,0);
      float ch = cc[hh];
      #pragma unroll
      for (int r=0;r<16;r++) ds[r] += exp2f(Sacc[r] + ch);
    }
    #pragma unroll
    for (int r=0;r<16;r++){
      int jo = (r&3)+8*(r>>2)+4*half;
      float e = f1 + f2s[jo];
      e = (e>=0.f)? e : 0.2f*e;
      float ev = exp2f(fmaf(e, LOG2E, ds[r]));
      ds[r] = ((mw>>jo)&1u) ? ev : 0.f;
    }
    L += asum16(ds);
    #pragma unroll
    for (int c=0;c<2;c++){
      u32 a01 = cvt_pk_bf16(ds[c*8+0], ds[c*8+1]);
      u32 a23 = cvt_pk_bf16(ds[c*8+2], ds[c*8+3]);
      u32 b01 = cvt_pk_bf16(ds[c*8+4], ds[c*8+5]);
      u32 b23 = cvt_pk_bf16(ds[c*8+6], ds[c*8+7]);
      u32 a01s = __shfl_xor(a01,32);
      u32 a23s = __shfl_xor(a23,32);
      u32 b01s = __shfl_xor(b01,32);
      u32 b23s = __shfl_xor(b23,32);
      FR bf;
      bf.u[0] = half? b01s : a01;
      bf.u[1] = half? b23s : a23;
      bf.u[2] = half? b01  : a01s;
      bf.u[3] = half? b23  : a23s;
      #pragma unroll
      for (int ch=0;ch<2;ch++){
        sh8 whA;
        {
          FR u;
          #pragma unroll
          for (int p=0;p<4;p++){
            int jl = c*16 + half*8 + 2*p;
            u.u[p]=cvt_pk_bf16(wt[jl*LROW + ch*32 + l31], wt[(jl+1)*LROW + ch*32 + l31]);
          }
          whA=u.s;
        }
        if (ch) C1 = __builtin_amdgcn_mfma_f32_32x32x16_bf16(whA, bf.s, C1, 0,0,0);
        else    C0 = __builtin_amdgcn_mfma_f32_32x32x16_bf16(whA, bf.s, C0, 0,0,0);
      }
    }
  }
  L = L + __shfl_xor(L,32);
  if (half==0){
    float* pb = p2ml + ((size_t)(h*S+sc)*2)*N + i;
    pb[0]=0.f; pb[(size_t)N]=L;
  }
  {
    float* pv = php + ((size_t)(h*S+sc)*N + i)*F;
    #pragma unroll
    for (int g=0;g<4;g++){
      *(float4*)(pv + 8*g + 4*half)      = make_float4(C0[g*4],C0[g*4+1],C0[g*4+2],C0[g*4+3]);
      *(float4*)(pv + 32 + 8*g + 4*half) = make_float4(C1[g*4],C1[g*4+1],C1[g*4+2],C1[g*4+3]);
    }
  }
}

// ---------------- stats1: per-(h,hh,row) combine of (m,l) across chunks ----------------
template<int S>
__global__ __launch_bounds__(256) void k_stats1(const float* __restrict__ pml, float* __restrict__ wgt1,
    float* __restrict__ mstar, float* __restrict__ invl, int N)
{
  const int h = blockIdx.y>>2, hh = blockIdx.y&3;
  const int row = blockIdx.x*256 + threadIdx.x;
  float mv[S];
  #pragma unroll
  for (int sc=0;sc<S;sc++) mv[sc]=pml[((size_t)((h*S+sc)*8)+hh)*N+row];
  float ms=-1e30f;
  #pragma unroll
  for (int sc=0;sc<S;sc++) ms=fmaxf(ms,mv[sc]);
  float ls=0.f;
  #pragma unroll
  for (int sc=0;sc<S;sc++){
    float w = exp2f(mv[sc]-ms);
    float lv = pml[((size_t)((h*S+sc)*8)+4+hh)*N+row];
    ls = fmaf(lv, w, ls);
    wgt1[((size_t)((h*S+sc)*4)+hh)*N+row]=w;
  }
  mstar[((size_t)(h*4+hh))*N+row]=ms;
  invl [((size_t)(h*4+hh))*N+row]=1.f/ls;
}

// ---------------- comb1: weighted chunk-sum + row softmax -> smw ----------------
template<int F, int S>
__global__ __launch_bounds__(256) void k_comb1(const float* __restrict__ pw, const float* __restrict__ wgt1,
    const float* __restrict__ invl, float* __restrict__ smw, int N)
{
  constexpr int D = F/4;
  constexpr int RPB = 256/F;
  const int h = blockIdx.y;
  const int c = threadIdx.x % F;
  const int row = blockIdx.x*RPB + threadIdx.x / F;
  const int hh = c / D;
  float acc=0.f;
  #pragma unroll
  for (int sc=0;sc<S;sc++){
    float w = wgt1[((size_t)((h*S+sc)*4)+hh)*N+row];
    float p = pw[((size_t)(h*S+sc)*N + row)*F + c];
    acc = fmaf(w,p,acc);
  }
  float w0 = acc * invl[((size_t)(h*4+hh))*N+row];
  float mx = wred_max<F>(w0);
  float e = exp2f((w0-mx)*LOG2E);
  float sm = wred_sum<F>(e);
  smw[((size_t)h*N+row)*F + c] = e/sm;
}

// ---------------- stats2 ----------------
template<int S>
__global__ __launch_bounds__(256) void k_stats2(const float* __restrict__ p2ml, float* __restrict__ wgt2,
    float* __restrict__ invL, int N)
{
  const int h = blockIdx.y;
  const int row = blockIdx.x*256 + threadIdx.x;
  float mv[S];
  #pragma unroll
  for (int sc=0;sc<S;sc++) mv[sc]=p2ml[((size_t)((h*S+sc)*2))*N+row];
  float M=-1e30f;
  #pragma unroll
  for (int sc=0;sc<S;sc++) M=fmaxf(M,mv[sc]);
  float L=0.f;
  #pragma unroll
  for (int sc=0;sc<S;sc++){
    float w=exp2f(mv[sc]-M);
    float lv=p2ml[((size_t)((h*S+sc)*2)+1)*N+row];
    L = fmaf(lv,w,L);
    wgt2[(size_t)(h*S+sc)*N+row]=w;
  }
  invL[(size_t)h*N+row]=1.f/L;
}

// ---------------- comb2 ----------------
template<int F, int S, bool L1OUT>
__global__ __launch_bounds__(256) void k_comb2(const float* __restrict__ php, const float* __restrict__ wgt2,
    const float* __restrict__ invL, const float* __restrict__ smw, void* __restrict__ outp, int N)
{
  constexpr int RPB = 256/F;
  const int h = blockIdx.y;
  const int c = threadIdx.x % F;
  const int row = blockIdx.x*RPB + threadIdx.x / F;
  float acc=0.f;
  #pragma unroll
  for (int sc=0;sc<S;sc++){
    float w = wgt2[(size_t)(h*S+sc)*N+row];
    float p = php[((size_t)(h*S+sc)*N + row)*F + c];
    acc = fmaf(w,p,acc);
  }
  float v = acc * invL[(size_t)h*N+row] + smw[((size_t)h*N+row)*F + c];
  v = (v>0.f)? v : expm1f(v);
  if (L1OUT){
    v = (v>0.f)? v : expm1f(v);
    ((float*)outp)[(size_t)row*(4*F) + h*F + c] = v;
  } else {
    ((float*)outp)[(size_t)row*F + c] = v;
  }
}

extern "C" void kernel_launch(void* const* d_in, const int* in_sizes, int n_in,
                              void* d_out, int out_size, void* d_ws, size_t ws_size,
                              hipStream_t stream)
{
  (void)in_sizes; (void)n_in; (void)out_size; (void)ws_size;
  const int N=3072;
  const int S1=8, S2=32;

  const float* x      = (const float*)d_in[0];
  const int*   adj    = (const int*)d_in[1];
  const float* W_h    = (const float*)d_in[2];
  const float* linW_h = (const float*)d_in[3];
  const float* linb_h = (const float*)d_in[4];
  const float* qkvW_h = (const float*)d_in[5];
  const float* qkvb_h = (const float*)d_in[6];
  const float* a_h    = (const float*)d_in[7];
  const float* W_o    = (const float*)d_in[8];
  const float* linW_o = (const float*)d_in[9];
  const float* linb_o = (const float*)d_in[10];
  const float* qkvW_o = (const float*)d_in[11];
  const float* qkvb_o = (const float*)d_in[12];
  const float* a_o    = (const float*)d_in[13];

  char* w = (char*)d_ws;
  auto alloc=[&](size_t bytes)->char*{ char* p=w; w += (bytes+255)&~(size_t)255; return p; };
  u32*   mkT   = (u32*)  alloc((size_t)N*(N/32)*4);
  float* Wh1   = (float*)alloc((size_t)4*N*32*4);
  float* q1    = (float*)alloc((size_t)4*N*32*4);
  float* k1    = (float*)alloc((size_t)4*N*32*4);
  float* v1    = (float*)alloc((size_t)4*N*32*4);
  float* f11   = (float*)alloc((size_t)4*N*4);
  float* f21   = (float*)alloc((size_t)4*N*4);
  float* smw1  = (float*)alloc((size_t)4*32*N*4);
  float* x1    = (float*)alloc((size_t)N*128*4);
  float* Wh2   = (float*)alloc((size_t)N*64*4);
  float* q2    = (float*)alloc((size_t)N*64*4);
  float* k2    = (float*)alloc((size_t)N*64*4);
  float* v2    = (float*)alloc((size_t)N*64*4);
  float* f12   = (float*)alloc((size_t)N*4);
  float* f22   = (float*)alloc((size_t)N*4);
  float* smw2  = (float*)alloc((size_t)64*N*4);
  float* mst   = (float*)alloc((size_t)16*N*4);
  float* ivl   = (float*)alloc((size_t)16*N*4);
  float* wgt1  = (float*)alloc((size_t)256*N*4);
  float* wgt2  = (float*)alloc((size_t)64*N*4);
  float* ivL   = (float*)alloc((size_t)4*N*4);
  float* pml   = (float*)alloc((size_t)512*N*4);
  float* pw    = (float*)alloc((size_t)2048*N*4);

  const float qs1 = 0.17677669529663687f * LOG2E;   // 32^-0.5 in log2 domain
  const float qs2 = 0.125f * LOG2E;                 // 64^-0.5 in log2 domain

  k_mask<96><<<dim3(N*(N/32)/256), 256, 0, stream>>>(adj, mkT, N);

  // ---- layer 1 (4 outer heads, F=32) ----
  k_pre_a<128,32><<<dim3(N/256,4),256,0,stream>>>(x, W_h, linW_h, linb_h, Wh1, N);
  k_pre_b<32><<<dim3(N/256,4),256,0,stream>>>(Wh1, qkvW_h, qkvb_h, a_h, q1,k1,v1,f11,f21,N);
  k_sweep1_mfma32<8><<<dim3(N/128,S1,4),256,0,stream>>>(q1,k1,v1,pml,pw,N,qs1);
  k_stats1<8><<<dim3(N/256,16),256,0,stream>>>(pml,wgt1,mst,ivl,N);
  k_comb1<32,8><<<dim3(N/8,4),256,0,stream>>>(pw,wgt1,ivl,smw1,N);
  k_sweep2_mfma32<8><<<dim3(N/128,S1,4),256,0,stream>>>(q1,k1,Wh1,f11,f21,mst,ivl,mkT,pml,pw,N,qs1);
  k_stats2<8><<<dim3(N/256,4),256,0,stream>>>(pml,wgt2,ivL,N);
  k_comb2<32,8,true><<<dim3(N/8,4),256,0,stream>>>(pw,wgt2,ivL,smw1,x1,N);

  // ---- layer 2 (F=64) ----
  k_pre_a<128,64><<<dim3(N/256,1),256,0,stream>>>(x1, W_o, linW_o, linb_o, Wh2, N);
  k_pre_b<64><<<dim3(N/256,1),256,0,stream>>>(Wh2, qkvW_o, qkvb_o, a_o, q2,k2,v2,f12,f22,N);
  k_sweep1_mfma64<32><<<dim3(N/128,S2,1),256,0,stream>>>(q2,k2,v2,pml,pw,N,qs2);
  k_stats1<32><<<dim3(N/256,4),256,0,stream>>>(pml,wgt1,mst,ivl,N);
  k_comb1<64,32><<<dim3(N/4,1),256,0,stream>>>(pw,wgt1,ivl,smw2,N);
  k_sweep2_mfma64<32><<<dim3(N/128,S2,1),256,0,stream>>>(q2,k2,Wh2,f12,f22,mst,ivl,mkT,pml,pw,N,qs2);
  k_stats2<32><<<dim3(N/256,1),256,0,stream>>>(pml,wgt2,ivL,N);
  k_comb2<64,32,false><<<dim3(N/4,1),256,0,stream>>>(pw,wgt2,ivL,smw2,d_out,N);
}

// Round 19
// 359.592 us; speedup vs baseline: 1.4715x; 1.4715x over previous
//
#include <hip/hip_runtime.h>
#include <hip/hip_bf16.h>

#define LOG2E 1.4426950408889634f
#define LOG2LOG2E 0.5287663729448977f

typedef unsigned int u32;
typedef float f32x16 __attribute__((ext_vector_type(16)));
typedef short sh8 __attribute__((ext_vector_type(8)));

union FR { u32 u[4]; sh8 s; };

__device__ __forceinline__ u32 cvt_pk_bf16(float lo, float hi){
  u32 r;
  asm volatile("v_cvt_pk_bf16_f32 %0, %1, %2" : "=v"(r) : "v"(lo), "v"(hi));
  return r;
}

__device__ __forceinline__ float asum16(const float* s){
  float a0=s[0]+s[8],  a1=s[1]+s[9],  a2=s[2]+s[10], a3=s[3]+s[11];
  float a4=s[4]+s[12], a5=s[5]+s[13], a6=s[6]+s[14], a7=s[7]+s[15];
  a0+=a4; a1+=a5; a2+=a6; a3+=a7;
  a0+=a2; a1+=a3;
  return a0+a1;
}

template<int W>
__device__ __forceinline__ float wred_max(float v){
  #pragma unroll
  for (int o=1;o<W;o<<=1) v = fmaxf(v, __shfl_xor(v,o));
  return v;
}
template<int W>
__device__ __forceinline__ float wred_sum(float v){
  #pragma unroll
  for (int o=1;o<W;o<<=1) v += __shfl_xor(v,o);
  return v;
}

// ---------------- adj -> bitmask (transposed: mkT[word][row]) ----------------
template<int NW>
__global__ __launch_bounds__(256) void k_mask(const int* __restrict__ adj, u32* __restrict__ mkT, int N){
  int id = blockIdx.x*256 + threadIdx.x;
  int row = id / NW, word = id - row*NW;
  const int4* src = (const int4*)(adj + (size_t)row*N + word*32);
  u32 m = 0;
  #pragma unroll
  for (int g=0; g<8; g++){
    int4 v = src[g];
    if (v.x>0) m |= 1u<<(g*4+0);
    if (v.y>0) m |= 1u<<(g*4+1);
    if (v.z>0) m |= 1u<<(g*4+2);
    if (v.w>0) m |= 1u<<(g*4+3);
  }
  mkT[(size_t)word*N + row] = m;
}

// ---------------- pre_a: Wh = (x @ W) @ linW + linb ----------------
template<int FIN, int F>
__global__ __launch_bounds__(256) void k_pre_a(const float* __restrict__ xg, const float* __restrict__ Wg,
    const float* __restrict__ lWg, const float* __restrict__ lbg, float* __restrict__ Whg, int N)
{
  const int h = blockIdx.y;
  const int row = blockIdx.x*256 + threadIdx.x;
  __shared__ float Wl[FIN*F];
  __shared__ float lWl[F*F];
  __shared__ float lbl[F];
  for (int i=threadIdx.x;i<FIN*F;i+=256) Wl[i]=Wg[(size_t)h*FIN*F+i];
  for (int i=threadIdx.x;i<F*F;i+=256) lWl[i]=lWg[(size_t)h*F*F+i];
  if (threadIdx.x<F) lbl[threadIdx.x]=lbg[h*F+threadIdx.x];
  __syncthreads();
  float t[F];
  #pragma unroll
  for (int c=0;c<F;c++) t[c]=0.f;
  const float4* xr = (const float4*)(xg + (size_t)row*FIN);
  for (int k4=0;k4<FIN/4;k4++){
    float4 xv = xr[k4];
    float xs[4]={xv.x,xv.y,xv.z,xv.w};
    #pragma unroll
    for (int kk=0;kk<4;kk++){
      float x1 = xs[kk];
      const float* wrow = Wl + (k4*4+kk)*F;
      #pragma unroll
      for (int c=0;c<F;c++) t[c] = fmaf(x1, wrow[c], t[c]);
    }
  }
  float wh[F];
  #pragma unroll
  for (int c=0;c<F;c++) wh[c]=lbl[c];
  #pragma unroll
  for (int k=0;k<F;k++){
    float tv=t[k];
    #pragma unroll
    for (int c=0;c<F;c++) wh[c]=fmaf(tv, lWl[k*F+c], wh[c]);
  }
  float4* dst=(float4*)(Whg + ((size_t)h*N+row)*F);
  #pragma unroll
  for (int c4=0;c4<F/4;c4++) dst[c4]=make_float4(wh[c4*4],wh[c4*4+1],wh[c4*4+2],wh[c4*4+3]);
}

// ---------------- pre_b v3: thread = (row, col-group); spill-proof + parallel ----------------
// Block: 256 threads = 64 rows x 4 col-groups (one group per wave -> qWl reads broadcast).
// Grid: (N/64, H). Each thread: wh[F] in regs (static), 3F/4 cols in 8-wide static chunks.
template<int F>
__global__ __launch_bounds__(256) void k_pre_b(const float* __restrict__ Whg, const float* __restrict__ qWg,
   const float* __restrict__ qbg, const float* __restrict__ ag,
   float* __restrict__ qg, float* __restrict__ kg, float* __restrict__ vg,
   float* __restrict__ f1g, float* __restrict__ f2g, int N)
{
  constexpr int CPG = 3*F/4;                 // cols per group (24 or 48)
  const int h = blockIdx.y;
  const int rl = threadIdx.x & 63;
  const int grp = threadIdx.x >> 6;
  const int row = blockIdx.x*64 + rl;
  __shared__ float qWl[F*3*F];
  __shared__ float qbl[3*F];
  __shared__ float al[2*F];
  for (int i=threadIdx.x;i<F*3*F;i+=256) qWl[i]=qWg[(size_t)h*F*3*F+i];
  if (threadIdx.x<3*F) qbl[threadIdx.x]=qbg[h*3*F+threadIdx.x];
  if (threadIdx.x<2*F) al[threadIdx.x]=ag[h*2*F+threadIdx.x];
  __syncthreads();
  float wh[F];
  {
    const float4* wsrc = (const float4*)(Whg + ((size_t)h*N+row)*F);
    #pragma unroll
    for (int c4=0;c4<F/4;c4++){
      float4 t = wsrc[c4];
      wh[c4*4]=t.x; wh[c4*4+1]=t.y; wh[c4*4+2]=t.z; wh[c4*4+3]=t.w;
    }
  }
  if (grp==0){
    float s=0.f;
    #pragma unroll
    for (int k=0;k<F;k++) s = fmaf(wh[k], al[k], s);
    f1g[(size_t)h*N+row]=s;
  } else if (grp==1){
    float s=0.f;
    #pragma unroll
    for (int k=0;k<F;k++) s = fmaf(wh[k], al[F+k], s);
    f2g[(size_t)h*N+row]=s;
  }
  size_t base = ((size_t)h*N+row)*F;
  #pragma unroll
  for (int cc=0; cc<CPG; cc+=8){
    const int c0 = grp*CPG + cc;             // 8-chunk, always within one of q/k/v
    float acc[8];
    #pragma unroll
    for (int j=0;j<8;j++) acc[j]=qbl[c0+j];
    for (int k=0;k<F;k++){
      float wv = wh[k];
      const float4* qw4 = (const float4*)(qWl + k*3*F + c0);
      float4 qa = qw4[0], qb = qw4[1];
      acc[0]=fmaf(wv,qa.x,acc[0]); acc[1]=fmaf(wv,qa.y,acc[1]);
      acc[2]=fmaf(wv,qa.z,acc[2]); acc[3]=fmaf(wv,qa.w,acc[3]);
      acc[4]=fmaf(wv,qb.x,acc[4]); acc[5]=fmaf(wv,qb.y,acc[5]);
      acc[6]=fmaf(wv,qb.z,acc[6]); acc[7]=fmaf(wv,qb.w,acc[7]);
    }
    int reg = c0 / F, off = c0 - reg*F;
    float* dst = (reg==0? qg : (reg==1? kg : vg)) + base + off;
    *(float4*)dst     = make_float4(acc[0],acc[1],acc[2],acc[3]);
    *(float4*)(dst+4) = make_float4(acc[4],acc[5],acc[6],acc[7]);
  }
}

// ---------------- sweep1 MFMA (layer1, F=32, d=8), fixed-max (m=0) ----------------
template<int S>
__global__ __launch_bounds__(256,4) void k_sweep1_mfma32(const float* __restrict__ qg, const float* __restrict__ kg,
    const float* __restrict__ vg, float* __restrict__ pml, float* __restrict__ pw, int N, float qscale)
{
  constexpr int F=32, LROW=33;
  const int h = blockIdx.z;
  const int sc = blockIdx.y;
  const int JC = N/S;
  const int wid = threadIdx.x>>6;
  const int lane = threadIdx.x&63;
  const int l31 = lane&31;
  const int half = lane>>5;
  const int itile = blockIdx.x*4 + wid;
  const int i = itile*32 + l31;
  __shared__ float vt[32*LROW];

  sh8 qf[4];
  {
    const float* qrow = qg + ((size_t)h*N + i)*F;
    #pragma unroll
    for (int hh=0;hh<4;hh++){
      FR u;
      #pragma unroll
      for (int p=0;p<4;p++){
        float lo = half? 0.f : qrow[hh*8+2*p]*qscale;
        float hi = half? 0.f : qrow[hh*8+2*p+1]*qscale;
        u.u[p] = cvt_pk_bf16(lo,hi);
      }
      qf[hh]=u.s;
    }
  }
  f32x16 C, Zv;
  #pragma unroll
  for (int r=0;r<16;r++){ C[r]=0.f; Zv[r]=0.f; }
  float l[4];
  #pragma unroll
  for (int hh=0;hh<4;hh++) l[hh]=0.f;
  const sh8 zf = {0,0,0,0,0,0,0,0};

  const int j0 = sc*JC;
  for (int jt=0; jt<JC; jt+=32){
    __syncthreads();
    {
      const float4* vs = (const float4*)(vg + ((size_t)h*N + j0+jt)*F);
      int idx = threadIdx.x;
      int j = idx>>3, c4 = idx&7;
      float4 b = vs[idx];
      float* vd = vt + j*LROW + c4*4;
      vd[0]=b.x; vd[1]=b.y; vd[2]=b.z; vd[3]=b.w;
    }
    __syncthreads();
    const float* krow = kg + ((size_t)h*N + j0+jt + l31)*F;
    sh8 vA[2];
    #pragma unroll
    for (int c=0;c<2;c++){
      FR u;
      #pragma unroll
      for (int p=0;p<4;p++){
        int jl = c*16 + half*8 + 2*p;
        u.u[p]=cvt_pk_bf16(vt[jl*LROW + l31], vt[(jl+1)*LROW + l31]);
      }
      vA[c]=u.s;
    }
    #pragma unroll
    for (int hh=0;hh<4;hh++){
      sh8 kf;
      {
        FR u;
        float4 ka = *(const float4*)(krow + hh*8);
        float4 kb = *(const float4*)(krow + hh*8 + 4);
        u.u[0]=cvt_pk_bf16(ka.x,ka.y);
        u.u[1]=cvt_pk_bf16(ka.z,ka.w);
        u.u[2]=cvt_pk_bf16(kb.x,kb.y);
        u.u[3]=cvt_pk_bf16(kb.z,kb.w);
        kf=u.s;   // upper K-half garbage harmless: qf upper half is 0
      }
      f32x16 Sacc = __builtin_amdgcn_mfma_f32_32x32x16_bf16(kf, qf[hh], Zv, 0,0,0);
      float p[16];
      #pragma unroll
      for (int r=0;r<16;r++) p[r] = exp2f(Sacc[r]);
      l[hh] += asum16(p);
      const bool own = ((l31>>3)==hh);
      #pragma unroll
      for (int c=0;c<2;c++){
        u32 a01 = cvt_pk_bf16(p[c*8+0], p[c*8+1]);
        u32 a23 = cvt_pk_bf16(p[c*8+2], p[c*8+3]);
        u32 b01 = cvt_pk_bf16(p[c*8+4], p[c*8+5]);
        u32 b23 = cvt_pk_bf16(p[c*8+6], p[c*8+7]);
        u32 a01s = __shfl_xor(a01,32);
        u32 a23s = __shfl_xor(a23,32);
        u32 b01s = __shfl_xor(b01,32);
        u32 b23s = __shfl_xor(b23,32);
        FR bf;
        bf.u[0] = half? b01s : a01;
        bf.u[1] = half? b23s : a23;
        bf.u[2] = half? b01  : a01s;
        bf.u[3] = half? b23  : a23s;
        sh8 av = own ? vA[c] : zf;
        C = __builtin_amdgcn_mfma_f32_32x32x16_bf16(av, bf.s, C, 0,0,0);
      }
    }
  }
  float lt[4];
  #pragma unroll
  for (int hh=0;hh<4;hh++) lt[hh] = l[hh] + __shfl_xor(l[hh],32);
  if (half==0){
    float* pb = pml + ((size_t)(h*S+sc)*8)*N + i;
    #pragma unroll
    for (int hh=0;hh<4;hh++){ pb[(size_t)hh*N]=0.f; pb[(size_t)(4+hh)*N]=lt[hh]; }
  }
  {
    float* pv = pw + ((size_t)(h*S+sc)*N + i)*F;
    #pragma unroll
    for (int hh=0;hh<4;hh++){
      *(float4*)(pv + 8*hh + 4*half) = make_float4(C[hh*4],C[hh*4+1],C[hh*4+2],C[hh*4+3]);
    }
  }
}

// ---------------- sweep2 MFMA (layer1, F=32, d=8), fixed-max, transposed mask ----------------
template<int S>
__global__ __launch_bounds__(256,4) void k_sweep2_mfma32(const float* __restrict__ qg, const float* __restrict__ kg,
    const float* __restrict__ whg, const float* __restrict__ f1g, const float* __restrict__ f2g,
    const float* __restrict__ mstar, const float* __restrict__ invl, const u32* __restrict__ mkT,
    float* __restrict__ p2ml, float* __restrict__ php, int N, float qscale)
{
  constexpr int F=32, LROW=33;
  const int h = blockIdx.z;
  const int sc = blockIdx.y;
  const int JC = N/S;
  const int wid = threadIdx.x>>6;
  const int lane = threadIdx.x&63;
  const int l31 = lane&31;
  const int half = lane>>5;
  const int itile = blockIdx.x*4 + wid;
  const int i = itile*32 + l31;
  __shared__ float wt[32*LROW];
  __shared__ float f2s[32];

  sh8 qf[4];
  {
    const float* qrow = qg + ((size_t)h*N + i)*F;
    #pragma unroll
    for (int hh=0;hh<4;hh++){
      FR u;
      #pragma unroll
      for (int p=0;p<4;p++){
        float lo = half? 0.f : qrow[hh*8+2*p]*qscale;
        float hi = half? 0.f : qrow[hh*8+2*p+1]*qscale;
        u.u[p] = cvt_pk_bf16(lo,hi);
      }
      qf[hh]=u.s;
    }
  }
  float cc[4];
  #pragma unroll
  for (int hh=0;hh<4;hh++){
    float msv = mstar[((size_t)(h*4+hh))*N+i];
    float ilv = invl [((size_t)(h*4+hh))*N+i];
    cc[hh] = log2f(ilv) - msv + LOG2LOG2E;
  }
  const float f1 = f1g[(size_t)h*N+i];
  f32x16 C, Zv;
  #pragma unroll
  for (int r=0;r<16;r++){ C[r]=0.f; Zv[r]=0.f; }
  float L=0.f;

  const int j0 = sc*JC;
  for (int jt=0; jt<JC; jt+=32){
    __syncthreads();
    {
      const float4* ws = (const float4*)(whg + ((size_t)h*N + j0+jt)*F);
      int idx = threadIdx.x;
      int j = idx>>3, c4 = idx&7;
      float4 b = ws[idx];
      float* wd = wt + j*LROW + c4*4;
      wd[0]=b.x; wd[1]=b.y; wd[2]=b.z; wd[3]=b.w;
      if (threadIdx.x<32) f2s[threadIdx.x] = f2g[(size_t)h*N + j0+jt+threadIdx.x];
    }
    __syncthreads();
    u32 mw = mkT[(size_t)((j0+jt)>>5)*N + i];     // coalesced transposed mask
    const float* krow = kg + ((size_t)h*N + j0+jt + l31)*F;
    float ds[16];
    #pragma unroll
    for (int r=0;r<16;r++) ds[r]=0.f;
    #pragma unroll
    for (int hh=0;hh<4;hh++){
      sh8 kf;
      {
        FR u;
        float4 ka = *(const float4*)(krow + hh*8);
        float4 kb = *(const float4*)(krow + hh*8 + 4);
        u.u[0]=cvt_pk_bf16(ka.x,ka.y);
        u.u[1]=cvt_pk_bf16(ka.z,ka.w);
        u.u[2]=cvt_pk_bf16(kb.x,kb.y);
        u.u[3]=cvt_pk_bf16(kb.z,kb.w);
        kf=u.s;
      }
      f32x16 Sacc = __builtin_amdgcn_mfma_f32_32x32x16_bf16(kf, qf[hh], Zv, 0,0,0);
      float ch = cc[hh];
      #pragma unroll
      for (int r=0;r<16;r++) ds[r] += exp2f(Sacc[r] + ch);
    }
    #pragma unroll
    for (int r=0;r<16;r++){
      int jo = (r&3)+8*(r>>2)+4*half;
      float e = f1 + f2s[jo];
      e = (e>=0.f)? e : 0.2f*e;
      float ev = exp2f(fmaf(e, LOG2E, ds[r]));
      ds[r] = ((mw>>jo)&1u) ? ev : 0.f;
    }
    L += asum16(ds);
    #pragma unroll
    for (int c=0;c<2;c++){
      sh8 whA;
      {
        FR u;
        #pragma unroll
        for (int p=0;p<4;p++){
          int jl = c*16 + half*8 + 2*p;
          u.u[p]=cvt_pk_bf16(wt[jl*LROW + l31], wt[(jl+1)*LROW + l31]);
        }
        whA=u.s;
      }
      u32 a01 = cvt_pk_bf16(ds[c*8+0], ds[c*8+1]);
      u32 a23 = cvt_pk_bf16(ds[c*8+2], ds[c*8+3]);
      u32 b01 = cvt_pk_bf16(ds[c*8+4], ds[c*8+5]);
      u32 b23 = cvt_pk_bf16(ds[c*8+6], ds[c*8+7]);
      u32 a01s = __shfl_xor(a01,32);
      u32 a23s = __shfl_xor(a23,32);
      u32 b01s = __shfl_xor(b01,32);
      u32 b23s = __shfl_xor(b23,32);
      FR bf;
      bf.u[0] = half? b01s : a01;
      bf.u[1] = half? b23s : a23;
      bf.u[2] = half? b01  : a01s;
      bf.u[3] = half? b23  : a23s;
      C = __builtin_amdgcn_mfma_f32_32x32x16_bf16(whA, bf.s, C, 0,0,0);
    }
  }
  L = L + __shfl_xor(L,32);
  if (half==0){
    float* pb = p2ml + ((size_t)(h*S+sc)*2)*N + i;
    pb[0]=0.f; pb[(size_t)N]=L;
  }
  {
    float* pv = php + ((size_t)(h*S+sc)*N + i)*F;
    #pragma unroll
    for (int g=0;g<4;g++)
      *(float4*)(pv + 8*g + 4*half) = make_float4(C[g*4],C[g*4+1],C[g*4+2],C[g*4+3]);
  }
}

// ---------------- sweep1 MFMA (layer2, F=64, d=16), fixed-max ----------------
template<int S>
__global__ __launch_bounds__(256,4) void k_sweep1_mfma64(const float* __restrict__ qg, const float* __restrict__ kg,
    const float* __restrict__ vg, float* __restrict__ pml, float* __restrict__ pw, int N, float qscale)
{
  constexpr int F=64, LROW=65;
  const int h = blockIdx.z;
  const int sc = blockIdx.y;
  const int JC = N/S;
  const int wid = threadIdx.x>>6;
  const int lane = threadIdx.x&63;
  const int l31 = lane&31;
  const int half = lane>>5;
  const int itile = blockIdx.x*4 + wid;
  const int i = itile*32 + l31;
  __shared__ float vt[32*LROW];

  sh8 qf[4];
  {
    const float* qrow = qg + ((size_t)h*N + i)*F;
    #pragma unroll
    for (int hh=0;hh<4;hh++){
      FR u;
      #pragma unroll
      for (int p=0;p<4;p++)
        u.u[p] = cvt_pk_bf16(qrow[hh*16 + 8*half + 2*p]*qscale, qrow[hh*16 + 8*half + 2*p+1]*qscale);
      qf[hh]=u.s;
    }
  }
  f32x16 C0, C1, Zv;
  #pragma unroll
  for (int r=0;r<16;r++){ C0[r]=0.f; C1[r]=0.f; Zv[r]=0.f; }
  float l[4];
  #pragma unroll
  for (int hh=0;hh<4;hh++) l[hh]=0.f;
  const sh8 zf = {0,0,0,0,0,0,0,0};

  const int j0 = sc*JC;
  for (int jt=0; jt<JC; jt+=32){
    __syncthreads();
    {
      const float4* vs = (const float4*)(vg + ((size_t)h*N + j0+jt)*F);
      #pragma unroll
      for (int q2=0;q2<2;q2++){
        int idx = q2*256 + threadIdx.x;
        int j = idx>>4, c4 = idx&15;
        float4 b = vs[idx];
        float* vd = vt + j*LROW + c4*4;
        vd[0]=b.x; vd[1]=b.y; vd[2]=b.z; vd[3]=b.w;
      }
    }
    __syncthreads();
    const float* krow = kg + ((size_t)h*N + j0+jt + l31)*F;
    sh8 vA[2][2];
    #pragma unroll
    for (int ch=0;ch<2;ch++)
      #pragma unroll
      for (int c=0;c<2;c++){
        FR u;
        #pragma unroll
        for (int p=0;p<4;p++){
          int jl = c*16 + half*8 + 2*p;
          u.u[p]=cvt_pk_bf16(vt[jl*LROW + ch*32 + l31], vt[(jl+1)*LROW + ch*32 + l31]);
        }
        vA[ch][c]=u.s;
      }
    #pragma unroll
    for (int hh=0;hh<4;hh++){
      sh8 kf;
      {
        FR u;
        float4 ka = *(const float4*)(krow + hh*16 + 8*half);
        float4 kb = *(const float4*)(krow + hh*16 + 8*half + 4);
        u.u[0]=cvt_pk_bf16(ka.x,ka.y);
        u.u[1]=cvt_pk_bf16(ka.z,ka.w);
        u.u[2]=cvt_pk_bf16(kb.x,kb.y);
        u.u[3]=cvt_pk_bf16(kb.z,kb.w);
        kf=u.s;
      }
      f32x16 Sacc = __builtin_amdgcn_mfma_f32_32x32x16_bf16(kf, qf[hh], Zv, 0,0,0);
      f32x16 &Cr = (hh>>1)? C1 : C0;
      float p[16];
      #pragma unroll
      for (int r=0;r<16;r++) p[r] = exp2f(Sacc[r]);
      l[hh] += asum16(p);
      const bool own = ((l31>>4) == (hh&1));
      #pragma unroll
      for (int c=0;c<2;c++){
        u32 a01 = cvt_pk_bf16(p[c*8+0], p[c*8+1]);
        u32 a23 = cvt_pk_bf16(p[c*8+2], p[c*8+3]);
        u32 b01 = cvt_pk_bf16(p[c*8+4], p[c*8+5]);
        u32 b23 = cvt_pk_bf16(p[c*8+6], p[c*8+7]);
        u32 a01s = __shfl_xor(a01,32);
        u32 a23s = __shfl_xor(a23,32);
        u32 b01s = __shfl_xor(b01,32);
        u32 b23s = __shfl_xor(b23,32);
        FR bf;
        bf.u[0] = half? b01s : a01;
        bf.u[1] = half? b23s : a23;
        bf.u[2] = half? b01  : a01s;
        bf.u[3] = half? b23  : a23s;
        sh8 av = own ? vA[hh>>1][c] : zf;
        Cr = __builtin_amdgcn_mfma_f32_32x32x16_bf16(av, bf.s, Cr, 0,0,0);
      }
    }
  }
  float lt[4];
  #pragma unroll
  for (int hh=0;hh<4;hh++) lt[hh] = l[hh] + __shfl_xor(l[hh],32);
  if (half==0){
    float* pb = pml + ((size_t)(h*S+sc)*8)*N + i;
    #pragma unroll
    for (int hh=0;hh<4;hh++){ pb[(size_t)hh*N]=0.f; pb[(size_t)(4+hh)*N]=lt[hh]; }
  }
  {
    float* pv = pw + ((size_t)(h*S+sc)*N + i)*F;
    #pragma unroll
    for (int g=0;g<4;g++){
      *(float4*)(pv + 8*g + 4*half)      = make_float4(C0[g*4],C0[g*4+1],C0[g*4+2],C0[g*4+3]);
      *(float4*)(pv + 32 + 8*g + 4*half) = make_float4(C1[g*4],C1[g*4+1],C1[g*4+2],C1[g*4+3]);
    }
  }
}

// ---------------- sweep2 MFMA (layer2, F=64, d=16), fixed-max, transposed mask ----------------
template<int S>
__global__ __launch_bounds__(256,4) void k_sweep2_mfma64(const float* __restrict__ qg, const float* __restrict__ kg,
    const float* __restrict__ whg, const float* __restrict__ f1g, const float* __restrict__ f2g,
    const float* __restrict__ mstar, const float* __restrict__ invl, const u32* __restrict__ mkT,
    float* __restrict__ p2ml, float* __restrict__ php, int N, float qscale)
{
  constexpr int F=64, LROW=65;
  const int h = blockIdx.z;
  const int sc = blockIdx.y;
  const int JC = N/S;
  const int wid = threadIdx.x>>6;
  const int lane = threadIdx.x&63;
  const int l31 = lane&31;
  const int half = lane>>5;
  const int itile = blockIdx.x*4 + wid;
  const int i = itile*32 + l31;
  __shared__ float wt[32*LROW];
  __shared__ float f2s[32];

  sh8 qf[4];
  {
    const float* qrow = qg + ((size_t)h*N + i)*F;
    #pragma unroll
    for (int hh=0;hh<4;hh++){
      FR u;
      #pragma unroll
      for (int p=0;p<4;p++)
        u.u[p] = cvt_pk_bf16(qrow[hh*16 + 8*half + 2*p]*qscale, qrow[hh*16 + 8*half + 2*p+1]*qscale);
      qf[hh]=u.s;
    }
  }
  float cc[4];
  #pragma unroll
  for (int hh=0;hh<4;hh++){
    float msv = mstar[((size_t)(h*4+hh))*N+i];
    float ilv = invl [((size_t)(h*4+hh))*N+i];
    cc[hh] = log2f(ilv) - msv + LOG2LOG2E;
  }
  const float f1 = f1g[(size_t)h*N+i];
  f32x16 C0, C1, Zv;
  #pragma unroll
  for (int r=0;r<16;r++){ C0[r]=0.f; C1[r]=0.f; Zv[r]=0.f; }
  float L=0.f;

  const int j0 = sc*JC;
  for (int jt=0; jt<JC; jt+=32){
    __syncthreads();
    {
      const float4* ws = (const float4*)(whg + ((size_t)h*N + j0+jt)*F);
      #pragma unroll
      for (int q2=0;q2<2;q2++){
        int idx = q2*256 + threadIdx.x;
        int j = idx>>4, c4 = idx&15;
        float4 b = ws[idx];
        float* wd = wt + j*LROW + c4*4;
        wd[0]=b.x; wd[1]=b.y; wd[2]=b.z; wd[3]=b.w;
      }
      if (threadIdx.x<32) f2s[threadIdx.x] = f2g[(size_t)h*N + j0+jt+threadIdx.x];
    }
    __syncthreads();
    u32 mw = mkT[(size_t)((j0+jt)>>5)*N + i];
    const float* krow = kg + ((size_t)h*N + j0+jt + l31)*F;
    float ds[16];
    #pragma unroll
    for (int r=0;r<16;r++) ds[r]=0.f;
    #pragma unroll
    for (int hh=0;hh<4;hh++){
      sh8 kf;
      {
        FR u;
        float4 ka = *(const float4*)(krow + hh*16 + 8*half);
        float4 kb = *(const float4*)(krow + hh*16 + 8*half + 4);
        u.u[0]=cvt_pk_bf16(ka.x,ka.y);
        u.u[1]=cvt_pk_bf16(ka.z,ka.w);
        u.u[2]=cvt_pk_bf16(kb.x,kb.y);
        u.u[3]=cvt_pk_bf16(kb.z,kb.w);
        kf=u.s;
      }
      f32x16 Sacc = __builtin_amdgcn_mfma_f32_32x32x16_bf16(kf, qf[hh], Zv, 0,0,0);
      float ch = cc[hh];
      #pragma unroll
      for (int r=0;r<16;r++) ds[r] += exp2f(Sacc[r] + ch);
    }
    #pragma unroll
    for (int r=0;r<16;r++){
      int jo = (r&3)+8*(r>>2)+4*half;
      float e = f1 + f2s[jo];
      e = (e>=0.f)? e : 0.2f*e;
      float ev = exp2f(fmaf(e, LOG2E, ds[r]));
      ds[r] = ((mw>>jo)&1u) ? ev : 0.f;
    }
    L += asum16(ds);
    #pragma unroll
    for (int c=0;c<2;c++){
      u32 a01 = cvt_pk_bf16(ds[c*8+0], ds[c*8+1]);
      u32 a23 = cvt_pk_bf16(ds[c*8+2], ds[c*8+3]);
      u32 b01 = cvt_pk_bf16(ds[c*8+4], ds[c*8+5]);
      u32 b23 = cvt_pk_bf16(ds[c*8+6], ds[c*8+7]);
      u32 a01s = __shfl_xor(a01,32);
      u32 a23s = __shfl_xor(a23,32);
      u32 b01s = __shfl_xor(b01,32);
      u32 b23s = __shfl_xor(b23,32);
      FR bf;
      bf.u[0] = half? b01s : a01;
      bf.u[1] = half? b23s : a23;
      bf.u[2] = half? b01  : a01s;
      bf.u[3] = half? b23  : a23s;
      #pragma unroll
      for (int ch=0;ch<2;ch++){
        sh8 whA;
        {
          FR u;
          #pragma unroll
          for (int p=0;p<4;p++){
            int jl = c*16 + half*8 + 2*p;
            u.u[p]=cvt_pk_bf16(wt[jl*LROW + ch*32 + l31], wt[(jl+1)*LROW + ch*32 + l31]);
          }
          whA=u.s;
        }
        if (ch) C1 = __builtin_amdgcn_mfma_f32_32x32x16_bf16(whA, bf.s, C1, 0,0,0);
        else    C0 = __builtin_amdgcn_mfma_f32_32x32x16_bf16(whA, bf.s, C0, 0,0,0);
      }
    }
  }
  L = L + __shfl_xor(L,32);
  if (half==0){
    float* pb = p2ml + ((size_t)(h*S+sc)*2)*N + i;
    pb[0]=0.f; pb[(size_t)N]=L;
  }
  {
    float* pv = php + ((size_t)(h*S+sc)*N + i)*F;
    #pragma unroll
    for (int g=0;g<4;g++){
      *(float4*)(pv + 8*g + 4*half)      = make_float4(C0[g*4],C0[g*4+1],C0[g*4+2],C0[g*4+3]);
      *(float4*)(pv + 32 + 8*g + 4*half) = make_float4(C1[g*4],C1[g*4+1],C1[g*4+2],C1[g*4+3]);
    }
  }
}

// ---------------- stats1: per-(h,hh,row) combine of (m,l) across chunks ----------------
template<int S>
__global__ __launch_bounds__(256) void k_stats1(const float* __restrict__ pml, float* __restrict__ wgt1,
    float* __restrict__ mstar, float* __restrict__ invl, int N)
{
  const int h = blockIdx.y>>2, hh = blockIdx.y&3;
  const int row = blockIdx.x*256 + threadIdx.x;
  float mv[S];
  #pragma unroll
  for (int sc=0;sc<S;sc++) mv[sc]=pml[((size_t)((h*S+sc)*8)+hh)*N+row];
  float ms=-1e30f;
  #pragma unroll
  for (int sc=0;sc<S;sc++) ms=fmaxf(ms,mv[sc]);
  float ls=0.f;
  #pragma unroll
  for (int sc=0;sc<S;sc++){
    float w = exp2f(mv[sc]-ms);
    float lv = pml[((size_t)((h*S+sc)*8)+4+hh)*N+row];
    ls = fmaf(lv, w, ls);
    wgt1[((size_t)((h*S+sc)*4)+hh)*N+row]=w;
  }
  mstar[((size_t)(h*4+hh))*N+row]=ms;
  invl [((size_t)(h*4+hh))*N+row]=1.f/ls;
}

// ---------------- comb1: weighted chunk-sum + row softmax -> smw ----------------
template<int F, int S>
__global__ __launch_bounds__(256) void k_comb1(const float* __restrict__ pw, const float* __restrict__ wgt1,
    const float* __restrict__ invl, float* __restrict__ smw, int N)
{
  constexpr int D = F/4;
  constexpr int RPB = 256/F;
  const int h = blockIdx.y;
  const int c = threadIdx.x % F;
  const int row = blockIdx.x*RPB + threadIdx.x / F;
  const int hh = c / D;
  float acc=0.f;
  #pragma unroll
  for (int sc=0;sc<S;sc++){
    float w = wgt1[((size_t)((h*S+sc)*4)+hh)*N+row];
    float p = pw[((size_t)(h*S+sc)*N + row)*F + c];
    acc = fmaf(w,p,acc);
  }
  float w0 = acc * invl[((size_t)(h*4+hh))*N+row];
  float mx = wred_max<F>(w0);
  float e = exp2f((w0-mx)*LOG2E);
  float sm = wred_sum<F>(e);
  smw[((size_t)h*N+row)*F + c] = e/sm;
}

// ---------------- stats2 ----------------
template<int S>
__global__ __launch_bounds__(256) void k_stats2(const float* __restrict__ p2ml, float* __restrict__ wgt2,
    float* __restrict__ invL, int N)
{
  const int h = blockIdx.y;
  const int row = blockIdx.x*256 + threadIdx.x;
  float mv[S];
  #pragma unroll
  for (int sc=0;sc<S;sc++) mv[sc]=p2ml[((size_t)((h*S+sc)*2))*N+row];
  float M=-1e30f;
  #pragma unroll
  for (int sc=0;sc<S;sc++) M=fmaxf(M,mv[sc]);
  float L=0.f;
  #pragma unroll
  for (int sc=0;sc<S;sc++){
    float w=exp2f(mv[sc]-M);
    float lv=p2ml[((size_t)((h*S+sc)*2)+1)*N+row];
    L = fmaf(lv,w,L);
    wgt2[(size_t)(h*S+sc)*N+row]=w;
  }
  invL[(size_t)h*N+row]=1.f/L;
}

// ---------------- comb2 ----------------
template<int F, int S, bool L1OUT>
__global__ __launch_bounds__(256) void k_comb2(const float* __restrict__ php, const float* __restrict__ wgt2,
    const float* __restrict__ invL, const float* __restrict__ smw, void* __restrict__ outp, int N)
{
  constexpr int RPB = 256/F;
  const int h = blockIdx.y;
  const int c = threadIdx.x % F;
  const int row = blockIdx.x*RPB + threadIdx.x / F;
  float acc=0.f;
  #pragma unroll
  for (int sc=0;sc<S;sc++){
    float w = wgt2[(size_t)(h*S+sc)*N+row];
    float p = php[((size_t)(h*S+sc)*N + row)*F + c];
    acc = fmaf(w,p,acc);
  }
  float v = acc * invL[(size_t)h*N+row] + smw[((size_t)h*N+row)*F + c];
  v = (v>0.f)? v : expm1f(v);
  if (L1OUT){
    v = (v>0.f)? v : expm1f(v);
    ((float*)outp)[(size_t)row*(4*F) + h*F + c] = v;
  } else {
    ((float*)outp)[(size_t)row*F + c] = v;
  }
}

extern "C" void kernel_launch(void* const* d_in, const int* in_sizes, int n_in,
                              void* d_out, int out_size, void* d_ws, size_t ws_size,
                              hipStream_t stream)
{
  (void)in_sizes; (void)n_in; (void)out_size; (void)ws_size;
  const int N=3072;
  const int S1=8, S2=32;

  const float* x      = (const float*)d_in[0];
  const int*   adj    = (const int*)d_in[1];
  const float* W_h    = (const float*)d_in[2];
  const float* linW_h = (const float*)d_in[3];
  const float* linb_h = (const float*)d_in[4];
  const float* qkvW_h = (const float*)d_in[5];
  const float* qkvb_h = (const float*)d_in[6];
  const float* a_h    = (const float*)d_in[7];
  const float* W_o    = (const float*)d_in[8];
  const float* linW_o = (const float*)d_in[9];
  const float* linb_o = (const float*)d_in[10];
  const float* qkvW_o = (const float*)d_in[11];
  const float* qkvb_o = (const float*)d_in[12];
  const float* a_o    = (const float*)d_in[13];

  char* w = (char*)d_ws;
  auto alloc=[&](size_t bytes)->char*{ char* p=w; w += (bytes+255)&~(size_t)255; return p; };
  u32*   mkT   = (u32*)  alloc((size_t)N*(N/32)*4);
  float* Wh1   = (float*)alloc((size_t)4*N*32*4);
  float* q1    = (float*)alloc((size_t)4*N*32*4);
  float* k1    = (float*)alloc((size_t)4*N*32*4);
  float* v1    = (float*)alloc((size_t)4*N*32*4);
  float* f11   = (float*)alloc((size_t)4*N*4);
  float* f21   = (float*)alloc((size_t)4*N*4);
  float* smw1  = (float*)alloc((size_t)4*32*N*4);
  float* x1    = (float*)alloc((size_t)N*128*4);
  float* Wh2   = (float*)alloc((size_t)N*64*4);
  float* q2    = (float*)alloc((size_t)N*64*4);
  float* k2    = (float*)alloc((size_t)N*64*4);
  float* v2    = (float*)alloc((size_t)N*64*4);
  float* f12   = (float*)alloc((size_t)N*4);
  float* f22   = (float*)alloc((size_t)N*4);
  float* smw2  = (float*)alloc((size_t)64*N*4);
  float* mst   = (float*)alloc((size_t)16*N*4);
  float* ivl   = (float*)alloc((size_t)16*N*4);
  float* wgt1  = (float*)alloc((size_t)256*N*4);
  float* wgt2  = (float*)alloc((size_t)64*N*4);
  float* ivL   = (float*)alloc((size_t)4*N*4);
  float* pml   = (float*)alloc((size_t)512*N*4);
  float* pw    = (float*)alloc((size_t)2048*N*4);

  const float qs1 = 0.17677669529663687f * LOG2E;   // 32^-0.5 in log2 domain
  const float qs2 = 0.125f * LOG2E;                 // 64^-0.5 in log2 domain

  k_mask<96><<<dim3(N*(N/32)/256), 256, 0, stream>>>(adj, mkT, N);

  // ---- layer 1 (4 outer heads, F=32) ----
  k_pre_a<128,32><<<dim3(N/256,4),256,0,stream>>>(x, W_h, linW_h, linb_h, Wh1, N);
  k_pre_b<32><<<dim3(N/64,4),256,0,stream>>>(Wh1, qkvW_h, qkvb_h, a_h, q1,k1,v1,f11,f21,N);
  k_sweep1_mfma32<8><<<dim3(N/128,S1,4),256,0,stream>>>(q1,k1,v1,pml,pw,N,qs1);
  k_stats1<8><<<dim3(N/256,16),256,0,stream>>>(pml,wgt1,mst,ivl,N);
  k_comb1<32,8><<<dim3(N/8,4),256,0,stream>>>(pw,wgt1,ivl,smw1,N);
  k_sweep2_mfma32<8><<<dim3(N/128,S1,4),256,0,stream>>>(q1,k1,Wh1,f11,f21,mst,ivl,mkT,pml,pw,N,qs1);
  k_stats2<8><<<dim3(N/256,4),256,0,stream>>>(pml,wgt2,ivL,N);
  k_comb2<32,8,true><<<dim3(N/8,4),256,0,stream>>>(pw,wgt2,ivL,smw1,x1,N);

  // ---- layer 2 (F=64) ----
  k_pre_a<128,64><<<dim3(N/256,1),256,0,stream>>>(x1, W_o, linW_o, linb_o, Wh2, N);
  k_pre_b<64><<<dim3(N/64,1),256,0,stream>>>(Wh2, qkvW_o, qkvb_o, a_o, q2,k2,v2,f12,f22,N);
  k_sweep1_mfma64<32><<<dim3(N/128,S2,1),256,0,stream>>>(q2,k2,v2,pml,pw,N,qs2);
  k_stats1<32><<<dim3(N/256,4),256,0,stream>>>(pml,wgt1,mst,ivl,N);
  k_comb1<64,32><<<dim3(N/4,1),256,0,stream>>>(pw,wgt1,ivl,smw2,N);
  k_sweep2_mfma64<32><<<dim3(N/128,S2,1),256,0,stream>>>(q2,k2,Wh2,f12,f22,mst,ivl,mkT,pml,pw,N,qs2);
  k_stats2<32><<<dim3(N/256,1),256,0,stream>>>(pml,wgt2,ivL,N);
  k_comb2<64,32,false><<<dim3(N/4,1),256,0,stream>>>(pw,wgt2,ivL,smw2,d_out,N);
}